// Round 1
// baseline (231.630 us; speedup 1.0000x reference)
//
#include <hip/hip_runtime.h>
#include <math.h>

// Problem: out[b,s,d] = x[b,s,d] + pe[s,d]
//   pe[s, 2i]   = sin(s / 10000^(2i/D))
//   pe[s, 2i+1] = cos(s / 10000^(2i/D))
// B=4, S=4096, D=2048 (fp32 in, fp32 out). Memory-bound: 256 MiB traffic.

#define PE_S 4096
#define PE_D 2048

__global__ __launch_bounds__(256)
void PositionalEncoding_84284438216797_kernel(const float* __restrict__ x,
                                              float* __restrict__ out,
                                              int batches) {
    // One thread handles one float4 of the (s,d) plane, applied to all batches.
    const int t = blockIdx.x * blockDim.x + threadIdx.x;   // 0 .. S*D/4-1
    const int e = t << 2;                                  // element index in [0, S*D)
    const int s = e >> 11;                                 // e / 2048
    const int d = e & (PE_D - 1);                          // e % 2048

    const float pos = (float)s;
    const int i0 = d >> 1;                                 // pair index of elements (d, d+1)
    // inv_freq(i) = 10000^(-2i/D) = exp2(-(2*log2(10000)/D) * i)
    const float c = (float)(2.0 * 13.287712379549449 / (double)PE_D);
    const float a0 = pos * exp2f(-c * (float)i0);
    const float a1 = pos * exp2f(-c * (float)(i0 + 1));

    float s0, c0, s1, c1;
    sincosf(a0, &s0, &c0);
    sincosf(a1, &s1, &c1);
    const float4 pe = make_float4(s0, c0, s1, c1);

    const size_t SD = (size_t)PE_S * (size_t)PE_D;
    size_t off = (size_t)e;
    #pragma unroll
    for (int b = 0; b < 4; ++b) {
        float4 v = *(const float4*)(x + off);
        v.x += pe.x; v.y += pe.y; v.z += pe.z; v.w += pe.w;
        *(float4*)(out + off) = v;
        off += SD;
    }
    (void)batches;
}

extern "C" void kernel_launch(void* const* d_in, const int* in_sizes, int n_in,
                              void* d_out, int out_size, void* d_ws, size_t ws_size,
                              hipStream_t stream) {
    const float* x = (const float*)d_in[0];
    float* out = (float*)d_out;
    // S*D/4 threads total (each covers 4 floats x 4 batches)
    const int n_threads = (PE_S * PE_D) / 4;
    const int block = 256;
    const int grid = n_threads / block;   // 8192 blocks
    PositionalEncoding_84284438216797_kernel<<<grid, block, 0, stream>>>(x, out, 4);
    (void)in_sizes; (void)n_in; (void)out_size; (void)d_ws; (void)ws_size;
}

// Round 3
// 228.355 us; speedup vs baseline: 1.0143x; 1.0143x over previous
//
#include <hip/hip_runtime.h>
#include <math.h>

// out[b,s,d] = x[b,s,d] + pe[s,d]
//   pe[s, 2i]   = sin(s * 10000^(-2i/D))
//   pe[s, 2i+1] = cos(s * 10000^(-2i/D))
// B=4, S=4096, D=2048, fp32. Memory-bound: 268 MB traffic, floor ~43 us.
//
// Angle computed in REVOLUTIONS (rev = rad / 2pi) so we can use the HW
// transcendentals v_sin_f32 / v_cos_f32 (input in revolutions, range-reduced
// with v_fract_f32) instead of libm sincosf's Payne-Hanek slow path at
// |x| ~ 4096 rad.
//
// Nontemporal builtins need native vector types, not HIP_vector_type structs.
typedef float f32x4 __attribute__((ext_vector_type(4)));

#define PE_S 4096
#define PE_D 2048

__global__ __launch_bounds__(256)
void PositionalEncoding_84284438216797_kernel(const float* __restrict__ x,
                                              float* __restrict__ out) {
    const int t = blockIdx.x * blockDim.x + threadIdx.x;   // 0 .. S*D/4-1
    const int e = t << 2;                                  // element index in [0, S*D)
    const int s = e >> 11;                                 // e / 2048
    const int d = e & (PE_D - 1);                          // e % 2048

    const float pos = (float)s;
    const int i0 = d >> 1;                                 // pair index for (d, d+1)

    // rev(i) = pos * 10000^(-2i/D) / (2pi) = pos * exp2(-c*i + log2(1/(2pi)))
    const float c = (float)(2.0 * 13.287712379549449 / (double)PE_D); // 2*log2(1e4)/D
    const float LOG2_INV_2PI = -2.6514961294723187f;       // log2(1/(2*pi))
    const float r0 = pos * exp2f(fmaf(-c, (float)i0, LOG2_INV_2PI));
    const float r1 = pos * exp2f(fmaf(-c, (float)(i0 + 1), LOG2_INV_2PI));

    const float f0 = __builtin_amdgcn_fractf(r0);          // reduce to [0,1) rev
    const float f1 = __builtin_amdgcn_fractf(r1);
    f32x4 pe;
    pe.x = __builtin_amdgcn_sinf(f0);
    pe.y = __builtin_amdgcn_cosf(f0);
    pe.z = __builtin_amdgcn_sinf(f1);
    pe.w = __builtin_amdgcn_cosf(f1);

    const size_t SD = (size_t)PE_S * (size_t)PE_D;
    const size_t o0 = (size_t)e;
    const size_t o1 = o0 + SD;
    const size_t o2 = o1 + SD;
    const size_t o3 = o2 + SD;

    // Issue all 4 loads before any store: 4x memory-level parallelism/thread.
    f32x4 v0 = __builtin_nontemporal_load((const f32x4*)(x + o0));
    f32x4 v1 = __builtin_nontemporal_load((const f32x4*)(x + o1));
    f32x4 v2 = __builtin_nontemporal_load((const f32x4*)(x + o2));
    f32x4 v3 = __builtin_nontemporal_load((const f32x4*)(x + o3));

    v0 += pe;
    v1 += pe;
    v2 += pe;
    v3 += pe;

    __builtin_nontemporal_store(v0, (f32x4*)(out + o0));
    __builtin_nontemporal_store(v1, (f32x4*)(out + o1));
    __builtin_nontemporal_store(v2, (f32x4*)(out + o2));
    __builtin_nontemporal_store(v3, (f32x4*)(out + o3));
}

extern "C" void kernel_launch(void* const* d_in, const int* in_sizes, int n_in,
                              void* d_out, int out_size, void* d_ws, size_t ws_size,
                              hipStream_t stream) {
    const float* x = (const float*)d_in[0];
    float* out = (float*)d_out;
    const int n_threads = (PE_S * PE_D) / 4;   // each thread: 1 float4 x 4 batches
    const int block = 256;
    const int grid = n_threads / block;        // 8192 blocks
    PositionalEncoding_84284438216797_kernel<<<grid, block, 0, stream>>>(x, out);
    (void)in_sizes; (void)n_in; (void)out_size; (void)d_ws; (void)ws_size;
}